// Round 10
// baseline (1311764.746 us; speedup 1.0000x reference)
//
#include <hip/hip_runtime.h>
#include <hip/hip_fp16.h>

#define H_ 1024
#define B_ 256
#define T_ 256
#define C_ 10

typedef _Float16 f16x8 __attribute__((ext_vector_type(8)));
typedef float f32x4 __attribute__((ext_vector_type(4)));

__device__ __forceinline__ float sigm_f(float v) { return 1.f / (1.f + __expf(-v)); }
__device__ __forceinline__ float tanh_f(float v) {
  v = fminf(fmaxf(v, -15.f), 15.f);
  float e = __expf(2.f * v);
  return (e - 1.f) / (e + 1.f);
}

// invalidate this CU's vector L1 and WAIT for completion. After this, plain
// loads are served by the shared XCD L2 (R9-proven consumer mechanism).
__device__ __forceinline__ void inv_l1_wait() {
  asm volatile("buffer_inv sc0\n\ts_waitcnt vmcnt(0)" ::: "memory");
}

// cross-XCD-safe coherence-point load (bypasses L1+L2) — slow-path h reads
__device__ __forceinline__ f16x8 load_h8_agent(const _Float16* p) {
  const unsigned long long* q = reinterpret_cast<const unsigned long long*>(p);
  unsigned long long lo = __hip_atomic_load(q,     __ATOMIC_RELAXED, __HIP_MEMORY_SCOPE_AGENT);
  unsigned long long hi = __hip_atomic_load(q + 1, __ATOMIC_RELAXED, __HIP_MEMORY_SCOPE_AGENT);
  union { unsigned long long u[2]; f16x8 v; } r;
  r.u[0] = lo; r.u[1] = hi;
  return r.v;
}

// zero flags/scal/h0 with agent-scope stores (write-through to IC). Dispatch
// boundaries (CP acquire at kernel start) make these visible to lstm_main.
__global__ void lstm_init(unsigned* __restrict__ flags, int flagDw,
                          unsigned* __restrict__ scal,
                          unsigned* __restrict__ h0u, int h0Dw) {
  int i = blockIdx.x * blockDim.x + threadIdx.x;
  int n = gridDim.x * blockDim.x;
  for (int k = i; k < flagDw; k += n)
    __hip_atomic_store(flags + k, 0u, __ATOMIC_RELAXED, __HIP_MEMORY_SCOPE_AGENT);
  for (int k = i; k < 1024; k += n)
    __hip_atomic_store(scal + k, 0u, __ATOMIC_RELAXED, __HIP_MEMORY_SCOPE_AGENT);
  for (int k = i; k < h0Dw; k += n)
    __hip_atomic_store(h0u + k, 0u, __ATOMIC_RELAXED, __HIP_MEMORY_SCOPE_AGENT);
}

// Persistent LSTM. 256 WGs = 32 row-groups (r) x 8 col-groups (g); each WG:
// 32 hidden units x 32 batch cols, all 4 gates; weights stationary in VGPRs
// (row permutation m = 4*u + gate). Col-groups are communication-CLOSED and
// co-located on one XCD (runtime vote, engaged since R7).
// FAST (R10): h in 2 parity buffers, L2-resident. Producers: TRUE plain
//   stores (workgroup-scope atomic store => sc0=sc1=0; NOT volatile, which
//   on gfx950 sets sc0+sc1 and bypasses L2 — the R7/R9 hidden cost).
//   Flags likewise plain. Consumers: buffer_inv sc0 + s_waitcnt before each
//   flag sample (flag/h addresses are reused each step), then plain loads
//   served by the shared XCD L2. Cross-dispatch coherence = CP dispatch
//   acquire/release.
// SLOW (vote failed): exact r6 agent-scope semantics.
// Both modes: identical FP ops in identical order -> identical bits.
__global__ __launch_bounds__(512, 2) void lstm_main(
    const float* __restrict__ x,
    const float* __restrict__ Wgh, const float* __restrict__ Wih,
    const float* __restrict__ Wfh, const float* __restrict__ Woh,
    const float* __restrict__ Wgx, const float* __restrict__ Wix,
    const float* __restrict__ Wfx, const float* __restrict__ Wox,
    const float* __restrict__ bg, const float* __restrict__ bi,
    const float* __restrict__ bf, const float* __restrict__ bo,
    _Float16* __restrict__ hT, unsigned int* __restrict__ flags,
    unsigned int* __restrict__ scal)
{
  const int bid  = blockIdx.x;
  const int g    = bid & 7;      // col group (one XCD, verified by vote)
  const int r    = bid >> 3;     // row group 0..31
  const int tid  = threadIdx.x;
  const int wid  = tid >> 6;     // wave 0..7
  const int lane = tid & 63;
  const int mg   = wid >> 2;     // M-group 0..1
  const int kg   = wid & 3;      // K-slice 0..3
  const int q    = lane >> 4;    // 0..3
  const int rlo  = lane & 15;
  const int c0   = g * 32;       // batch col base
  const size_t HB = (size_t)B_ * H_;

  __shared__ float part[32 * 4 * 128];  // [c_local][kg][m] f32, XOR-swizzled
  __shared__ unsigned mode_sh;

  // ---- per-col-group XCD co-location vote (machinery proven r3-r9) --------
  {
    unsigned xcc;
    asm volatile("s_getreg_b32 %0, hwreg(HW_REG_XCC_ID)" : "=s"(xcc));
    if (tid == 0) {
      unsigned* mask  = scal + g;
      unsigned* ready = scal + 8 + g;
      __hip_atomic_fetch_or(mask, 1u << (xcc & 31),
                            __ATOMIC_RELAXED, __HIP_MEMORY_SCOPE_AGENT);
      __hip_atomic_fetch_add(ready, 1u, __ATOMIC_RELEASE, __HIP_MEMORY_SCOPE_AGENT);
      int gd = 0; bool trip = false;
      while (__hip_atomic_load(ready, __ATOMIC_RELAXED, __HIP_MEMORY_SCOPE_AGENT) < 32u) {
        if (++gd > (1 << 22)) { trip = true; break; }
        __builtin_amdgcn_s_sleep(8);
      }
      unsigned m = __hip_atomic_load(mask, __ATOMIC_ACQUIRE, __HIP_MEMORY_SCOPE_AGENT);
      mode_sh = (!trip && __popc((int)m) == 1) ? 1u : 2u;
    }
    __syncthreads();
  }
  const bool fast = (mode_sh == 1u);

  // ---- A fragments: stationary weights in registers -----------------------
  f16x8 A[32];
  {
    const int gate = rlo & 3;
    const float* Wsel = (gate == 0) ? Wgh : (gate == 1) ? Wih : (gate == 2) ? Wfh : Woh;
    #pragma unroll
    for (int f = 0; f < 32; ++f) {
      const int mt  = f >> 3, kkl = f & 7;
      const int u   = mg * 16 + mt * 4 + (rlo >> 2);
      const int k   = kg * 256 + kkl * 32 + q * 8;
      const float4* p = reinterpret_cast<const float4*>(
          Wsel + (size_t)(r * 32 + u) * H_ + k);
      float4 lo = p[0], hi = p[1];
      f16x8 a;
      a[0]=(_Float16)lo.x; a[1]=(_Float16)lo.y; a[2]=(_Float16)lo.z; a[3]=(_Float16)lo.w;
      a[4]=(_Float16)hi.x; a[5]=(_Float16)hi.y; a[6]=(_Float16)hi.z; a[7]=(_Float16)hi.w;
      A[f] = a;
    }
  }

  // ---- per-thread elementwise constants -----------------------------------
  const int c_l = tid >> 4;
  const int uu  = tid & 15;
  float wx0[4], wx1[4], bb0[4], bb1[4];
  {
    const int u0 = r * 32 + uu, u1 = u0 + 16;
    wx0[0]=Wgx[u0]; wx0[1]=Wix[u0]; wx0[2]=Wfx[u0]; wx0[3]=Wox[u0];
    wx1[0]=Wgx[u1]; wx1[1]=Wix[u1]; wx1[2]=Wfx[u1]; wx1[3]=Wox[u1];
    bb0[0]=bg[u0];  bb0[1]=bi[u0];  bb0[2]=bf[u0];  bb0[3]=bo[u0];
    bb1[0]=bg[u1];  bb1[1]=bi[u1];  bb1[2]=bf[u1];  bb1[3]=bo[u1];
  }
  float cs0 = 0.f, cs1 = 0.f;
  const float* xrow = x + (size_t)(c0 + c_l) * T_;

  unsigned int* myflags = flags + ((size_t)(g * 32 + kg * 8 + (lane & 7)) * 16);
  unsigned int* ownflag = flags + ((size_t)(g * 32 + r) * 16);

  for (int t = 0; t < T_; ++t) {
    // ---- per-wave wait: only the 8 producers feeding this K-slice ----
    if (t > 0) {
      const unsigned tgt = (unsigned)t;
      int guard = 0;
      if (fast) {
        // flags + h live in the shared XCD L2; flag/h addresses are reused
        // every step, so invalidate our L1 (and wait) before each sample.
        for (;;) {
          inv_l1_wait();
          unsigned v = tgt;
          if (lane < 8)
            v = __hip_atomic_load(myflags, __ATOMIC_RELAXED,
                                  __HIP_MEMORY_SCOPE_WORKGROUP);
          if (__all((int)(v >= tgt))) break;
          if (++guard > (1 << 15)) break;  // wrong model => fast absmax fail
          __builtin_amdgcn_s_sleep(1);
        }
      } else {
        for (;;) {
          unsigned v = tgt;
          if (lane < 8)
            v = __hip_atomic_load(myflags, __ATOMIC_RELAXED,
                                  __HIP_MEMORY_SCOPE_AGENT);
          if (__all((int)(v >= tgt))) break;
          if (++guard > (1 << 20)) break;
          __builtin_amdgcn_s_sleep(1);
        }
      }
      asm volatile("" ::: "memory");
    }

    const _Float16* hbr = hT + (size_t)(t & 1) * HB;
    _Float16*       hbw = hT + (size_t)((t + 1) & 1) * HB;

    // ---- B-fragment loads: plain/L2 (fast; L1 inv'd in poll) or IC (slow) --
    const _Float16* hb0 = hbr + (size_t)(c0 + rlo) * H_ + kg * 256 + q * 8;
    const _Float16* hb1 = hb0 + 16 * (size_t)H_;

    f16x8 B0[8], B1[8];
    if (fast) {
      #pragma unroll
      for (int kkl = 0; kkl < 8; ++kkl) {
        B0[kkl] = *reinterpret_cast<const f16x8*>(hb0 + kkl * 32);
        B1[kkl] = *reinterpret_cast<const f16x8*>(hb1 + kkl * 32);
      }
    } else {
      #pragma unroll
      for (int kkl = 0; kkl < 8; ++kkl) {
        B0[kkl] = load_h8_agent(hb0 + kkl * 32);
        B1[kkl] = load_h8_agent(hb1 + kkl * 32);
      }
    }

    // ---- GEMM: preactivations for this WG's 128(M) x 32(N) tile ----
    f32x4 acc[4][2];
    #pragma unroll
    for (int mt = 0; mt < 4; ++mt) {
      acc[mt][0] = (f32x4){0.f, 0.f, 0.f, 0.f};
      acc[mt][1] = (f32x4){0.f, 0.f, 0.f, 0.f};
    }
    #pragma unroll
    for (int kkl = 0; kkl < 8; ++kkl) {
      #pragma unroll
      for (int mt = 0; mt < 4; ++mt) {
        acc[mt][0] = __builtin_amdgcn_mfma_f32_16x16x32_f16(A[mt*8+kkl], B0[kkl], acc[mt][0], 0, 0, 0);
        acc[mt][1] = __builtin_amdgcn_mfma_f32_16x16x32_f16(A[mt*8+kkl], B1[kkl], acc[mt][1], 0, 0, 0);
      }
    }

    // ---- K-partials to LDS (C/D layout: col=lane&15, row=(lane>>4)*4+reg) ----
    #pragma unroll
    for (int mt = 0; mt < 4; ++mt) {
      #pragma unroll
      for (int nt = 0; nt < 2; ++nt) {
        const int c_loc = nt * 16 + rlo;
        const int m = mg * 64 + mt * 16 + 4 * q;
        unsigned addr = (unsigned)(c_loc * 2048 + kg * 512 + m * 4);
        addr ^= (unsigned)((c_loc & 7) << 4);
        *reinterpret_cast<f32x4*>(reinterpret_cast<char*>(part) + addr) = acc[mt][nt];
      }
    }
    __syncthreads();

    // ---- reduce over kg + gate nonlinearities + state update ----
    const float xv = xrow[t];
    unsigned short hbits0, hbits1;
    {
      unsigned lin = (unsigned)(c_l * 2048 + uu * 16);
      f32x4 s = *reinterpret_cast<const f32x4*>(
          reinterpret_cast<const char*>(part) + (lin ^ ((unsigned)(c_l & 7) << 4)));
      #pragma unroll
      for (int kgi = 1; kgi < 4; ++kgi) {
        unsigned l2 = lin + (unsigned)(kgi * 512);
        s += *reinterpret_cast<const f32x4*>(
            reinterpret_cast<const char*>(part) + (l2 ^ ((unsigned)(c_l & 7) << 4)));
      }
      float pg = s[0] + wx0[0]*xv + bb0[0];
      float pi = s[1] + wx0[1]*xv + bb0[1];
      float pf = s[2] + wx0[2]*xv + bb0[2];
      float po = s[3] + wx0[3]*xv + bb0[3];
      float gg = tanh_f(pg), ii = sigm_f(pi), ff = sigm_f(pf), oo = sigm_f(po);
      cs0 = gg * ii + cs0 * ff;
      hbits0 = __builtin_bit_cast(unsigned short, (_Float16)(tanh_f(cs0) * oo));
    }
    {
      unsigned lin = (unsigned)(c_l * 2048 + (uu + 16) * 16);
      f32x4 s = *reinterpret_cast<const f32x4*>(
          reinterpret_cast<const char*>(part) + (lin ^ ((unsigned)(c_l & 7) << 4)));
      #pragma unroll
      for (int kgi = 1; kgi < 4; ++kgi) {
        unsigned l2 = lin + (unsigned)(kgi * 512);
        s += *reinterpret_cast<const f32x4*>(
            reinterpret_cast<const char*>(part) + (l2 ^ ((unsigned)(c_l & 7) << 4)));
      }
      float pg = s[0] + wx1[0]*xv + bb1[0];
      float pi = s[1] + wx1[1]*xv + bb1[1];
      float pf = s[2] + wx1[2]*xv + bb1[2];
      float po = s[3] + wx1[3]*xv + bb1[3];
      float gg = tanh_f(pg), ii = sigm_f(pi), ff = sigm_f(pf), oo = sigm_f(po);
      cs1 = gg * ii + cs1 * ff;
      hbits1 = __builtin_bit_cast(unsigned short, (_Float16)(tanh_f(cs1) * oo));
    }

    // ---- store h(t+1) ----
    {
      _Float16* hout = hbw + (size_t)(c0 + c_l) * H_ + r * 32;
      int nb0 = __shfl_down((int)hbits0, 1);
      int nb1 = __shfl_down((int)hbits1, 1);
      if ((uu & 1) == 0) {
        unsigned v0 = (unsigned)hbits0 | ((unsigned)(unsigned short)nb0 << 16);
        unsigned v1 = (unsigned)hbits1 | ((unsigned)(unsigned short)nb1 << 16);
        unsigned int* p0 = reinterpret_cast<unsigned int*>(hout + uu);
        unsigned int* p1 = reinterpret_cast<unsigned int*>(hout + uu + 16);
        if (fast && t != T_ - 1) {
          // TRUE plain stores (sc0=sc1=0): ack at and stay in the shared
          // XCD L2. (volatile would set sc0+sc1 and bypass to the IC.)
          __hip_atomic_store(p0, v0, __ATOMIC_RELAXED, __HIP_MEMORY_SCOPE_WORKGROUP);
          __hip_atomic_store(p1, v1, __ATOMIC_RELAXED, __HIP_MEMORY_SCOPE_WORKGROUP);
        } else {
          // slow mode + final step both modes (lstm_proj reads next dispatch)
          __hip_atomic_store(p0, v0, __ATOMIC_RELAXED, __HIP_MEMORY_SCOPE_AGENT);
          __hip_atomic_store(p1, v1, __ATOMIC_RELAXED, __HIP_MEMORY_SCOPE_AGENT);
        }
      }
    }
    // drain: h stores acked (L2 fast / IC slow) before the flag publishes
    asm volatile("s_waitcnt vmcnt(0)" ::: "memory");
    __syncthreads();
    if (tid == 0) {
      if (fast)
        __hip_atomic_store(ownflag, (unsigned)(t + 1),
                           __ATOMIC_RELAXED, __HIP_MEMORY_SCOPE_WORKGROUP);
      else
        __hip_atomic_store(ownflag, (unsigned)(t + 1),
                           __ATOMIC_RELAXED, __HIP_MEMORY_SCOPE_AGENT);
    }
  }
}

// out[b][cls] = sum_u W_ph[cls][u] * h_final[u][b] + b_p[cls]
__global__ void lstm_proj(const _Float16* __restrict__ hfin,
                          const float* __restrict__ Wph,
                          const float* __restrict__ bp,
                          float* __restrict__ out)
{
  const int b = blockIdx.x;
  const int l = threadIdx.x;
  const _Float16* hrow = hfin + (size_t)b * H_;
  float p[C_];
  #pragma unroll
  for (int cls = 0; cls < C_; ++cls) p[cls] = 0.f;
  for (int u = l; u < H_; u += 64) {
    float hv = (float)hrow[u];
    #pragma unroll
    for (int cls = 0; cls < C_; ++cls) p[cls] += hv * Wph[cls * H_ + u];
  }
  #pragma unroll
  for (int cls = 0; cls < C_; ++cls) {
    float v = p[cls];
    #pragma unroll
    for (int off = 32; off > 0; off >>= 1) v += __shfl_down(v, off);
    if (l == 0) out[b * C_ + cls] = v + bp[cls];
  }
}

extern "C" void kernel_launch(void* const* d_in, const int* in_sizes, int n_in,
                              void* d_out, int out_size, void* d_ws, size_t ws_size,
                              hipStream_t stream) {
  const float* x   = (const float*)d_in[0];
  const float* Wgx = (const float*)d_in[1];
  const float* Wgh = (const float*)d_in[2];
  const float* Wix = (const float*)d_in[3];
  const float* Wih = (const float*)d_in[4];
  const float* Wfx = (const float*)d_in[5];
  const float* Wfh = (const float*)d_in[6];
  const float* Wox = (const float*)d_in[7];
  const float* Woh = (const float*)d_in[8];
  const float* Wph = (const float*)d_in[9];
  const float* bg  = (const float*)d_in[10];
  const float* bi  = (const float*)d_in[11];
  const float* bf  = (const float*)d_in[12];
  const float* bo  = (const float*)d_in[13];
  const float* bp  = (const float*)d_in[14];
  float* out = (float*)d_out;

  // ws layout: [0,1MB) hT fp16 parity buffers [2][B][H];
  //            [1MB,+16KB) per-producer flags (256 x 64B);
  //            [1MB+16KB,+4KB) vote scalars
  _Float16* hT = (_Float16*)d_ws;
  const size_t hT_bytes = (size_t)2 * B_ * H_ * sizeof(_Float16);  // 1 MiB
  unsigned int* flags = (unsigned int*)((char*)d_ws + hT_bytes);
  unsigned int* scal  = (unsigned int*)((char*)d_ws + hT_bytes + 16384);

  lstm_init<<<256, 256, 0, stream>>>(flags, 4096, scal,
                                     (unsigned*)hT, (int)(B_ * H_ / 2));
  lstm_main<<<256, 512, 0, stream>>>(x, Wgh, Wih, Wfh, Woh,
                                     Wgx, Wix, Wfx, Wox,
                                     bg, bi, bf, bo, hT, flags, scal);
  lstm_proj<<<256, 64, 0, stream>>>(hT, Wph, bp, out);
}

// Round 11
// 1891.733 us; speedup vs baseline: 693.4195x; 693.4195x over previous
//
#include <hip/hip_runtime.h>
#include <hip/hip_fp16.h>

#define H_ 1024
#define B_ 256
#define T_ 256
#define C_ 10
#define SENT32 0x7FFF7FFFu   // fp16 (NaN,NaN): impossible as h output (|h|<1)

typedef _Float16 f16x8 __attribute__((ext_vector_type(8)));
typedef float f32x4 __attribute__((ext_vector_type(4)));
typedef unsigned int u32x4 __attribute__((ext_vector_type(4)));
typedef unsigned long long u64;

__device__ __forceinline__ float sigm_f(float v) { return 1.f / (1.f + __expf(-v)); }
__device__ __forceinline__ float tanh_f(float v) {
  v = fminf(fmaxf(v, -15.f), 15.f);
  float e = __expf(2.f * v);
  return (e - 1.f) / (e + 1.f);
}

// sc1 16B load: bypass L1/L2, read at the coherence point (IC). Issue-only;
// caller batches with one s_waitcnt vmcnt(0) + sched_barrier (rule #18).
#define GL16_SC1(dst, addr) \
  asm volatile("global_load_dwordx4 %0, %1, off sc1" : "=v"(dst) : "v"(addr))

// Per-launch init: flags=0; h buffer 0 = h(0) = 0; rot buffers 1..256 =
// sentinel. Agent stores (write-through to IC) so lstm_main's sc1 reads see
// them regardless of which XCD's L2 anything sits in.
__global__ void lstm_init(unsigned* __restrict__ flags, u64* __restrict__ h,
                          int rot) {
  const size_t i = (size_t)blockIdx.x * blockDim.x + threadIdx.x;
  const size_t n = (size_t)gridDim.x * blockDim.x;
  for (size_t k = i; k < 4096; k += n)
    __hip_atomic_store(flags + k, 0u, __ATOMIC_RELAXED, __HIP_MEMORY_SCOPE_AGENT);
  const size_t bufQ = (size_t)B_ * H_ / 4;   // u64 per h buffer (65536)
  for (size_t k = i; k < bufQ; k += n)
    __hip_atomic_store(h + k, (u64)0, __ATOMIC_RELAXED, __HIP_MEMORY_SCOPE_AGENT);
  if (rot) {
    const u64 s = 0x7FFF7FFF7FFF7FFFull;
    for (size_t k = bufQ + i; k < 257 * bufQ; k += n)
      __hip_atomic_store(h + k, s, __ATOMIC_RELAXED, __HIP_MEMORY_SCOPE_AGENT);
  }
}

// Persistent LSTM. 256 WGs = 32 row-groups (r) x 8 col-groups (g); each WG:
// 32 hidden units x 32 batch cols, all 4 gates; weights stationary in VGPRs
// (row permutation m = 4*u + gate; lane's f32x4 acc = 4 gates of one
// (unit,col)).
// R11 sync protocol (rot=1): NO flags, NO votes, NO drains. h rotates through
// 257 write-once buffers pre-filled with a sentinel that valid h data can
// never equal. Producers fire sc1 stores (agent/IC — the only channel proven
// visible on gfx950: R3/4/5/8/10 showed nothing weaker propagates) and move
// on. Consumers sc1-load their B fragments and retry only chunks still
// holding sentinel words: the data is its own readiness flag, per 16B chunk.
// FP op order is byte-identical to the r6/r9 kernels -> identical bits.
// rot=0 fallback: the r6 flag-ordered agent path.
__global__ __launch_bounds__(512, 2) void lstm_main(
    const float* __restrict__ x,
    const float* __restrict__ Wgh, const float* __restrict__ Wih,
    const float* __restrict__ Wfh, const float* __restrict__ Woh,
    const float* __restrict__ Wgx, const float* __restrict__ Wix,
    const float* __restrict__ Wfx, const float* __restrict__ Wox,
    const float* __restrict__ bg, const float* __restrict__ bi,
    const float* __restrict__ bf, const float* __restrict__ bo,
    _Float16* __restrict__ hT, unsigned int* __restrict__ flags, int rot)
{
  const int bid  = blockIdx.x;
  const int g    = bid & 7;      // col group
  const int r    = bid >> 3;     // row group 0..31
  const int tid  = threadIdx.x;
  const int wid  = tid >> 6;     // wave 0..7
  const int lane = tid & 63;
  const int mg   = wid >> 2;     // M-group 0..1
  const int kg   = wid & 3;      // K-slice 0..3
  const int q    = lane >> 4;    // 0..3
  const int rlo  = lane & 15;
  const int c0   = g * 32;       // batch col base
  const size_t HB = (size_t)B_ * H_;

  __shared__ float part[32 * 4 * 128];  // [c_local][kg][m] f32, XOR-swizzled

  // ---- A fragments: stationary weights in registers -----------------------
  f16x8 A[32];
  {
    const int gate = rlo & 3;
    const float* Wsel = (gate == 0) ? Wgh : (gate == 1) ? Wih : (gate == 2) ? Wfh : Woh;
    #pragma unroll
    for (int f = 0; f < 32; ++f) {
      const int mt  = f >> 3, kkl = f & 7;
      const int u   = mg * 16 + mt * 4 + (rlo >> 2);
      const int k   = kg * 256 + kkl * 32 + q * 8;
      const float4* p = reinterpret_cast<const float4*>(
          Wsel + (size_t)(r * 32 + u) * H_ + k);
      float4 lo = p[0], hi = p[1];
      f16x8 a;
      a[0]=(_Float16)lo.x; a[1]=(_Float16)lo.y; a[2]=(_Float16)lo.z; a[3]=(_Float16)lo.w;
      a[4]=(_Float16)hi.x; a[5]=(_Float16)hi.y; a[6]=(_Float16)hi.z; a[7]=(_Float16)hi.w;
      A[f] = a;
    }
  }

  // ---- per-thread elementwise constants -----------------------------------
  const int c_l = tid >> 4;
  const int uu  = tid & 15;
  float wx0[4], wx1[4], bb0[4], bb1[4];
  {
    const int u0 = r * 32 + uu, u1 = u0 + 16;
    wx0[0]=Wgx[u0]; wx0[1]=Wix[u0]; wx0[2]=Wfx[u0]; wx0[3]=Wox[u0];
    wx1[0]=Wgx[u1]; wx1[1]=Wix[u1]; wx1[2]=Wfx[u1]; wx1[3]=Wox[u1];
    bb0[0]=bg[u0];  bb0[1]=bi[u0];  bb0[2]=bf[u0];  bb0[3]=bo[u0];
    bb1[0]=bg[u1];  bb1[1]=bi[u1];  bb1[2]=bf[u1];  bb1[3]=bo[u1];
  }
  float cs0 = 0.f, cs1 = 0.f;
  const float* xrow = x + (size_t)(c0 + c_l) * T_;

  unsigned int* myflags = flags + ((size_t)(g * 32 + kg * 8 + (lane & 7)) * 16);
  unsigned int* ownflag = flags + ((size_t)(g * 32 + r) * 16);

  for (int t = 0; t < T_; ++t) {
    const _Float16* hbr = hT + (size_t)(rot ? t : (t & 1)) * HB;
    _Float16*       hbw = hT + (size_t)(rot ? (t + 1) : ((t + 1) & 1)) * HB;

    // ---- fallback only: flag poll (r6-proven) ----
    if (!rot && t > 0) {
      const unsigned tgt = (unsigned)t;
      int guard = 0;
      for (;;) {
        unsigned v = tgt;
        if (lane < 8)
          v = __hip_atomic_load(myflags, __ATOMIC_RELAXED, __HIP_MEMORY_SCOPE_AGENT);
        if (__all((int)(v >= tgt))) break;
        if (++guard > (1 << 20)) break;
        __builtin_amdgcn_s_sleep(1);
      }
      asm volatile("" ::: "memory");
    }

    // ---- B-fragment loads with per-chunk sentinel-validity retry ----
    const _Float16* hb0 = hbr + (size_t)(c0 + rlo) * H_ + kg * 256 + q * 8;
    const _Float16* hb1 = hb0 + 16 * (size_t)H_;

    u32x4 ch[16];
    {
      unsigned inval = 0xFFFFu;
      int rounds = 0;
      for (;;) {
        #pragma unroll
        for (int j = 0; j < 16; ++j) {
          if (inval & (1u << j)) {
            const _Float16* a = (j < 8) ? (hb0 + j * 32) : (hb1 + (j - 8) * 32);
            GL16_SC1(ch[j], a);
          }
        }
        asm volatile("s_waitcnt vmcnt(0)" ::: "memory");
        __builtin_amdgcn_sched_barrier(0);
        if (!rot) break;           // fallback: flag already ordered the data
        unsigned nv = 0;
        #pragma unroll
        for (int j = 0; j < 16; ++j) {
          if (inval & (1u << j)) {
            u32x4 v = ch[j];
            if (v[0] == SENT32 || v[1] == SENT32 ||
                v[2] == SENT32 || v[3] == SENT32)
              nv |= (1u << j);
          }
        }
        inval = nv;
        if (!__any((int)inval)) break;
        if (++rounds > (1 << 11)) break;  // fail-loud: NaNs -> absmax, no hang
        __builtin_amdgcn_s_sleep(1);
      }
    }
    f16x8 B0[8], B1[8];
    #pragma unroll
    for (int j = 0; j < 8; ++j) {
      B0[j] = __builtin_bit_cast(f16x8, ch[j]);
      B1[j] = __builtin_bit_cast(f16x8, ch[8 + j]);
    }

    // ---- GEMM: preactivations for this WG's 128(M) x 32(N) tile ----
    f32x4 acc[4][2];
    #pragma unroll
    for (int mt = 0; mt < 4; ++mt) {
      acc[mt][0] = (f32x4){0.f, 0.f, 0.f, 0.f};
      acc[mt][1] = (f32x4){0.f, 0.f, 0.f, 0.f};
    }
    #pragma unroll
    for (int kkl = 0; kkl < 8; ++kkl) {
      #pragma unroll
      for (int mt = 0; mt < 4; ++mt) {
        acc[mt][0] = __builtin_amdgcn_mfma_f32_16x16x32_f16(A[mt*8+kkl], B0[kkl], acc[mt][0], 0, 0, 0);
        acc[mt][1] = __builtin_amdgcn_mfma_f32_16x16x32_f16(A[mt*8+kkl], B1[kkl], acc[mt][1], 0, 0, 0);
      }
    }

    // ---- K-partials to LDS (C/D layout: col=lane&15, row=(lane>>4)*4+reg) ----
    #pragma unroll
    for (int mt = 0; mt < 4; ++mt) {
      #pragma unroll
      for (int nt = 0; nt < 2; ++nt) {
        const int c_loc = nt * 16 + rlo;
        const int m = mg * 64 + mt * 16 + 4 * q;
        unsigned addr = (unsigned)(c_loc * 2048 + kg * 512 + m * 4);
        addr ^= (unsigned)((c_loc & 7) << 4);
        *reinterpret_cast<f32x4*>(reinterpret_cast<char*>(part) + addr) = acc[mt][nt];
      }
    }
    __syncthreads();

    // ---- reduce over kg + gate nonlinearities + state update ----
    const float xv = xrow[t];
    unsigned short hbits0, hbits1;
    {
      unsigned lin = (unsigned)(c_l * 2048 + uu * 16);
      f32x4 s = *reinterpret_cast<const f32x4*>(
          reinterpret_cast<const char*>(part) + (lin ^ ((unsigned)(c_l & 7) << 4)));
      #pragma unroll
      for (int kgi = 1; kgi < 4; ++kgi) {
        unsigned l2 = lin + (unsigned)(kgi * 512);
        s += *reinterpret_cast<const f32x4*>(
            reinterpret_cast<const char*>(part) + (l2 ^ ((unsigned)(c_l & 7) << 4)));
      }
      float pg = s[0] + wx0[0]*xv + bb0[0];
      float pi = s[1] + wx0[1]*xv + bb0[1];
      float pf = s[2] + wx0[2]*xv + bb0[2];
      float po = s[3] + wx0[3]*xv + bb0[3];
      float gg = tanh_f(pg), ii = sigm_f(pi), ff = sigm_f(pf), oo = sigm_f(po);
      cs0 = gg * ii + cs0 * ff;
      hbits0 = __builtin_bit_cast(unsigned short, (_Float16)(tanh_f(cs0) * oo));
    }
    {
      unsigned lin = (unsigned)(c_l * 2048 + (uu + 16) * 16);
      f32x4 s = *reinterpret_cast<const f32x4*>(
          reinterpret_cast<const char*>(part) + (lin ^ ((unsigned)(c_l & 7) << 4)));
      #pragma unroll
      for (int kgi = 1; kgi < 4; ++kgi) {
        unsigned l2 = lin + (unsigned)(kgi * 512);
        s += *reinterpret_cast<const f32x4*>(
            reinterpret_cast<const char*>(part) + (l2 ^ ((unsigned)(c_l & 7) << 4)));
      }
      float pg = s[0] + wx1[0]*xv + bb1[0];
      float pi = s[1] + wx1[1]*xv + bb1[1];
      float pf = s[2] + wx1[2]*xv + bb1[2];
      float po = s[3] + wx1[3]*xv + bb1[3];
      float gg = tanh_f(pg), ii = sigm_f(pi), ff = sigm_f(pf), oo = sigm_f(po);
      cs1 = gg * ii + cs1 * ff;
      hbits1 = __builtin_bit_cast(unsigned short, (_Float16)(tanh_f(cs1) * oo));
    }

    // ---- store h(t+1): sc1 fire-and-forget (write-once buffer => no drain,
    // no flag; values self-validate at the consumer) ----
    {
      _Float16* hout = hbw + (size_t)(c0 + c_l) * H_ + r * 32;
      int nb0 = __shfl_down((int)hbits0, 1);
      int nb1 = __shfl_down((int)hbits1, 1);
      if ((uu & 1) == 0) {
        unsigned v0 = (unsigned)hbits0 | ((unsigned)(unsigned short)nb0 << 16);
        unsigned v1 = (unsigned)hbits1 | ((unsigned)(unsigned short)nb1 << 16);
        __hip_atomic_store(reinterpret_cast<unsigned int*>(hout + uu), v0,
                           __ATOMIC_RELAXED, __HIP_MEMORY_SCOPE_AGENT);
        __hip_atomic_store(reinterpret_cast<unsigned int*>(hout + uu + 16), v1,
                           __ATOMIC_RELAXED, __HIP_MEMORY_SCOPE_AGENT);
      }
    }
    if (!rot) {
      // fallback ordering: drain, barrier, publish flag (r6-proven)
      asm volatile("s_waitcnt vmcnt(0)" ::: "memory");
      __syncthreads();
      if (tid == 0)
        __hip_atomic_store(ownflag, (unsigned)(t + 1),
                           __ATOMIC_RELAXED, __HIP_MEMORY_SCOPE_AGENT);
    } else {
      __syncthreads();   // LDS partials reuse only; no memory ordering needed
    }
  }
}

// out[b][cls] = sum_u W_ph[cls][u] * h_final[u][b] + b_p[cls]
__global__ void lstm_proj(const _Float16* __restrict__ hfin,
                          const float* __restrict__ Wph,
                          const float* __restrict__ bp,
                          float* __restrict__ out)
{
  const int b = blockIdx.x;
  const int l = threadIdx.x;
  const _Float16* hrow = hfin + (size_t)b * H_;
  float p[C_];
  #pragma unroll
  for (int cls = 0; cls < C_; ++cls) p[cls] = 0.f;
  for (int u = l; u < H_; u += 64) {
    float hv = (float)hrow[u];
    #pragma unroll
    for (int cls = 0; cls < C_; ++cls) p[cls] += hv * Wph[cls * H_ + u];
  }
  #pragma unroll
  for (int cls = 0; cls < C_; ++cls) {
    float v = p[cls];
    #pragma unroll
    for (int off = 32; off > 0; off >>= 1) v += __shfl_down(v, off);
    if (l == 0) out[b * C_ + cls] = v + bp[cls];
  }
}

extern "C" void kernel_launch(void* const* d_in, const int* in_sizes, int n_in,
                              void* d_out, int out_size, void* d_ws, size_t ws_size,
                              hipStream_t stream) {
  const float* x   = (const float*)d_in[0];
  const float* Wgx = (const float*)d_in[1];
  const float* Wgh = (const float*)d_in[2];
  const float* Wix = (const float*)d_in[3];
  const float* Wih = (const float*)d_in[4];
  const float* Wfx = (const float*)d_in[5];
  const float* Wfh = (const float*)d_in[6];
  const float* Wox = (const float*)d_in[7];
  const float* Woh = (const float*)d_in[8];
  const float* Wph = (const float*)d_in[9];
  const float* bg  = (const float*)d_in[10];
  const float* bi  = (const float*)d_in[11];
  const float* bf  = (const float*)d_in[12];
  const float* bo  = (const float*)d_in[13];
  const float* bp  = (const float*)d_in[14];
  float* out = (float*)d_out;

  const size_t HB  = (size_t)B_ * H_;             // elems per h buffer
  const size_t HBb = HB * sizeof(_Float16);       // 512 KiB
  // ws layout: [0,16KB) flags (fallback); [1MB, 1MB + 257*512KB) h rotation
  // (buffer 0 = h(0); buffer t+1 = h after step t; write-once per launch).
  const size_t need = (1u << 20) + 257 * HBb;     // ~132.6 MB
  const int rot = (ws_size >= need) ? 1 : 0;

  unsigned* flags = (unsigned*)d_ws;
  _Float16* hT    = (_Float16*)((char*)d_ws + (1u << 20));

  lstm_init<<<2048, 256, 0, stream>>>(flags, (u64*)hT, rot);
  lstm_main<<<256, 512, 0, stream>>>(x, Wgh, Wih, Wfh, Woh,
                                     Wgx, Wix, Wfx, Wox,
                                     bg, bi, bf, bo, hT, flags, rot);
  lstm_proj<<<256, 64, 0, stream>>>(hT + (size_t)(rot ? T_ : 0) * HB,
                                    Wph, bp, out);
}

// Round 12
// 1504.128 us; speedup vs baseline: 872.1098x; 1.2577x over previous
//
#include <hip/hip_runtime.h>
#include <hip/hip_fp16.h>

#define H_ 1024
#define B_ 256
#define T_ 256
#define C_ 10
#define SENT32 0x7F7F7F7Fu  // memset 0x7F: fp16 0x7F7F = NaN, unreachable (|h|<1)

typedef _Float16 f16x8 __attribute__((ext_vector_type(8)));
typedef float f32x4 __attribute__((ext_vector_type(4)));
typedef unsigned int u32x4 __attribute__((ext_vector_type(4)));

__device__ __forceinline__ float sigm_f(float v) { return 1.f / (1.f + __expf(-v)); }
__device__ __forceinline__ float tanh_f(float v) {
  v = fminf(fmaxf(v, -15.f), 15.f);
  float e = __expf(2.f * v);
  return (e - 1.f) / (e + 1.f);
}

// sc1 16B load (IC / coherence point — the only proven-visible channel).
// Issue-only; caller does s_waitcnt + sched_barrier (rule #18).
#define GL16_SC1(dst, addr) \
  asm volatile("global_load_dwordx4 %0, %1, off sc1" : "=v"(dst) : "v"(addr) : "memory")

// Persistent LSTM. 256 WGs = 32 row-groups (r) x 8 col-groups (g); each WG:
// 32 units x 32 cols, all 4 gates; weights stationary in VGPRs (row perm
// m = 4*u + gate). R12: each step is split into col-phases A (cols 0-15) and
// B (cols 16-31) — independent recurrence chains. Phase X's B-fragments are
// PREFETCHED during phase !X (A-half of h(t+1) is complete mid-step, B-half
// at step end), so the ~0.8us IC load latency hides under the other phase's
// MFMA+reduce+EW. h rotates through 257 write-once sentinel-filled buffers
// (R11-proven): data self-validates -> no flags, no drains, no polls.
// Raw s_barrier + explicit lgkmcnt (NOT __syncthreads, which drains vmcnt and
// would kill the in-flight prefetch). FP order identical to R6/R9/R11 ->
// bit-identical output. rot=0 fallback: flag-ordered agent path per phase.
__global__ __launch_bounds__(512, 2) void lstm_main(
    const float* __restrict__ x,
    const float* __restrict__ Wgh, const float* __restrict__ Wih,
    const float* __restrict__ Wfh, const float* __restrict__ Woh,
    const float* __restrict__ Wgx, const float* __restrict__ Wix,
    const float* __restrict__ Wfx, const float* __restrict__ Wox,
    const float* __restrict__ bg, const float* __restrict__ bi,
    const float* __restrict__ bf, const float* __restrict__ bo,
    _Float16* __restrict__ hT, unsigned int* __restrict__ flags, int rot)
{
  const int bid  = blockIdx.x;
  const int g    = bid & 7;
  const int r    = bid >> 3;
  const int tid  = threadIdx.x;
  const int wid  = tid >> 6;
  const int lane = tid & 63;
  const int mg   = wid >> 2;
  const int kg   = wid & 3;
  const int q    = lane >> 4;
  const int rlo  = lane & 15;
  const int c0   = g * 32;
  const size_t HB = (size_t)B_ * H_;

  __shared__ float part[16 * 4 * 128];  // 32 KB partials (one phase)
  __shared__ float xl[32 * T_];         // 32 KB x slice (keeps x out of vmcnt)

  // ---- stage x rows c0..c0+31 (contiguous) into LDS ----
  {
    const float4* xs = reinterpret_cast<const float4*>(x + (size_t)c0 * T_);
    float4* xd = reinterpret_cast<float4*>(xl);
    #pragma unroll
    for (int i = 0; i < 4; ++i) xd[tid + i * 512] = xs[tid + i * 512];
  }

  // ---- A fragments: stationary weights in registers ----
  f16x8 A[32];
  {
    const int gate = rlo & 3;
    const float* Wsel = (gate == 0) ? Wgh : (gate == 1) ? Wih : (gate == 2) ? Wfh : Woh;
    #pragma unroll
    for (int f = 0; f < 32; ++f) {
      const int mt  = f >> 3, kkl = f & 7;
      const int u   = mg * 16 + mt * 4 + (rlo >> 2);
      const int k   = kg * 256 + kkl * 32 + q * 8;
      const float4* p = reinterpret_cast<const float4*>(
          Wsel + (size_t)(r * 32 + u) * H_ + k);
      float4 lo = p[0], hi = p[1];
      f16x8 a;
      a[0]=(_Float16)lo.x; a[1]=(_Float16)lo.y; a[2]=(_Float16)lo.z; a[3]=(_Float16)lo.w;
      a[4]=(_Float16)hi.x; a[5]=(_Float16)hi.y; a[6]=(_Float16)hi.z; a[7]=(_Float16)hi.w;
      A[f] = a;
    }
  }

  // ---- per-thread EW constants: one (unit, col) per phase ----
  const int cA = tid >> 5;   // col within half (A: c0+cA, B: c0+16+cA)
  const int un = tid & 31;   // unit within WG's 32
  float wx[4], bb[4];
  {
    const int u0 = r * 32 + un;
    wx[0]=Wgx[u0]; wx[1]=Wix[u0]; wx[2]=Wfx[u0]; wx[3]=Wox[u0];
    bb[0]=bg[u0];  bb[1]=bi[u0];  bb[2]=bf[u0];  bb[3]=bo[u0];
  }
  float csA = 0.f, csB = 0.f;

  unsigned int* myflags = flags + ((size_t)(g * 32 + kg * 8 + (lane & 7)) * 16);
  unsigned int* ownflag = flags + ((size_t)(g * 32 + r) * 16);

  asm volatile("s_waitcnt vmcnt(0)" ::: "memory");
  __syncthreads();  // xl + weights ready (prologue: full sync is fine)

  u32x4 ch0[8], ch1[8];
  // prologue: issue A-half loads for t=0 (buffer 0 = zeros)
  {
    const _Float16* p = hT + (size_t)(c0 + rlo) * H_ + kg * 256 + q * 8;
    #pragma unroll
    for (int j = 0; j < 8; ++j) GL16_SC1(ch0[j], p + j * 32);
  }

  for (int t = 0; t < T_; ++t) {
    const _Float16* hbr = hT + (size_t)(rot ? t : (t & 1)) * HB;
    _Float16*       hbw = hT + (size_t)(rot ? (t + 1) : ((t + 1) & 1)) * HB;
    const _Float16* hb0 = hbr + (size_t)(c0 + rlo) * H_ + kg * 256 + q * 8;
    const _Float16* hb1 = hb0 + 16 * (size_t)H_;

    // ================= PHASE A (cols 0-15) =================
    if (!rot && t > 0) {
      const unsigned tgt = 2u * (unsigned)t - 1u;   // producers' phase A of t-1
      int gd = 0;
      for (;;) {
        unsigned v = tgt;
        if (lane < 8)
          v = __hip_atomic_load(myflags, __ATOMIC_RELAXED, __HIP_MEMORY_SCOPE_AGENT);
        if (__all((int)(v >= tgt))) break;
        if (++gd > (1 << 20)) break;
        __builtin_amdgcn_s_sleep(1);
      }
      asm volatile("" ::: "memory");
      #pragma unroll
      for (int j = 0; j < 8; ++j) GL16_SC1(ch0[j], hb0 + j * 32);
    }
    asm volatile("s_waitcnt vmcnt(0)" ::: "memory");
    __builtin_amdgcn_sched_barrier(0);
    if (rot) {  // sentinel validity retry (usually passes first try)
      unsigned inval = 0xFFu; int rounds = 0;
      for (;;) {
        unsigned nv = 0;
        #pragma unroll
        for (int j = 0; j < 8; ++j) if (inval & (1u << j)) {
          u32x4 v = ch0[j];
          if (v[0]==SENT32 || v[1]==SENT32 || v[2]==SENT32 || v[3]==SENT32)
            nv |= (1u << j);
        }
        inval = nv;
        if (!__any((int)inval)) break;
        if (++rounds > (1 << 12)) break;  // fail-loud: NaNs -> absmax, no hang
        __builtin_amdgcn_s_sleep(1);
        #pragma unroll
        for (int j = 0; j < 8; ++j) if (inval & (1u << j)) GL16_SC1(ch0[j], hb0 + j * 32);
        asm volatile("s_waitcnt vmcnt(0)" ::: "memory");
        __builtin_amdgcn_sched_barrier(0);
      }
    }
    f16x8 B0[8];
    #pragma unroll
    for (int j = 0; j < 8; ++j) B0[j] = __builtin_bit_cast(f16x8, ch0[j]);

    if (rot) {  // prefetch B-half of h(t): published at end of producers' t-1
      #pragma unroll
      for (int j = 0; j < 8; ++j) GL16_SC1(ch1[j], hb1 + j * 32);
    }

    f32x4 accA[4];
    #pragma unroll
    for (int mt = 0; mt < 4; ++mt) accA[mt] = (f32x4){0.f,0.f,0.f,0.f};
    #pragma unroll
    for (int kkl = 0; kkl < 8; ++kkl)
      #pragma unroll
      for (int mt = 0; mt < 4; ++mt)
        accA[mt] = __builtin_amdgcn_mfma_f32_16x16x32_f16(A[mt*8+kkl], B0[kkl], accA[mt], 0,0,0);

    #pragma unroll
    for (int mt = 0; mt < 4; ++mt) {
      const int m = mg * 64 + mt * 16 + 4 * q;
      unsigned addr = (unsigned)(rlo * 2048 + kg * 512 + m * 4);
      addr ^= (unsigned)((rlo & 7) << 4);
      *reinterpret_cast<f32x4*>(reinterpret_cast<char*>(part) + addr) = accA[mt];
    }
    if (rot) { asm volatile("s_waitcnt lgkmcnt(0)" ::: "memory"); __builtin_amdgcn_s_barrier(); }
    else __syncthreads();

    {
      unsigned lin = (unsigned)(cA * 2048 + un * 16);
      f32x4 s = *reinterpret_cast<const f32x4*>(
          reinterpret_cast<const char*>(part) + (lin ^ ((unsigned)(cA & 7) << 4)));
      #pragma unroll
      for (int kgi = 1; kgi < 4; ++kgi) {
        unsigned l2 = lin + (unsigned)(kgi * 512);
        s += *reinterpret_cast<const f32x4*>(
            reinterpret_cast<const char*>(part) + (l2 ^ ((unsigned)(cA & 7) << 4)));
      }
      const float xv = xl[cA * T_ + t];
      float pg = s[0] + wx[0]*xv + bb[0];
      float pi = s[1] + wx[1]*xv + bb[1];
      float pf = s[2] + wx[2]*xv + bb[2];
      float po = s[3] + wx[3]*xv + bb[3];
      float gg = tanh_f(pg), ii = sigm_f(pi), ff = sigm_f(pf), oo = sigm_f(po);
      csA = gg * ii + csA * ff;
      unsigned short hbits = __builtin_bit_cast(unsigned short, (_Float16)(tanh_f(csA) * oo));
      int nb = __shfl_down((int)hbits, 1);
      if (!(un & 1)) {
        unsigned v = (unsigned)hbits | ((unsigned)(unsigned short)nb << 16);
        __hip_atomic_store(reinterpret_cast<unsigned*>(
            hbw + (size_t)(c0 + cA) * H_ + r * 32 + un),
            v, __ATOMIC_RELAXED, __HIP_MEMORY_SCOPE_AGENT);
      }
      asm volatile("" ::: "memory");
    }
    if (!rot) {
      asm volatile("s_waitcnt vmcnt(0)" ::: "memory");
      __syncthreads();
      if (tid == 0) __hip_atomic_store(ownflag, 2u*(unsigned)t + 1u,
                                       __ATOMIC_RELAXED, __HIP_MEMORY_SCOPE_AGENT);
    } else {
      __builtin_amdgcn_s_barrier();   // LDS part reuse only (no vmcnt drain!)
    }

    // ================= PHASE B (cols 16-31) =================
    if (!rot) {
      if (t > 0) {
        const unsigned tgt = 2u * (unsigned)t;      // producers' phase B of t-1
        int gd = 0;
        for (;;) {
          unsigned v = tgt;
          if (lane < 8)
            v = __hip_atomic_load(myflags, __ATOMIC_RELAXED, __HIP_MEMORY_SCOPE_AGENT);
          if (__all((int)(v >= tgt))) break;
          if (++gd > (1 << 20)) break;
          __builtin_amdgcn_s_sleep(1);
        }
        asm volatile("" ::: "memory");
      }
      #pragma unroll
      for (int j = 0; j < 8; ++j) GL16_SC1(ch1[j], hb1 + j * 32);
    }
    asm volatile("s_waitcnt vmcnt(0)" ::: "memory");
    __builtin_amdgcn_sched_barrier(0);
    if (rot) {
      unsigned inval = 0xFFu; int rounds = 0;
      for (;;) {
        unsigned nv = 0;
        #pragma unroll
        for (int j = 0; j < 8; ++j) if (inval & (1u << j)) {
          u32x4 v = ch1[j];
          if (v[0]==SENT32 || v[1]==SENT32 || v[2]==SENT32 || v[3]==SENT32)
            nv |= (1u << j);
        }
        inval = nv;
        if (!__any((int)inval)) break;
        if (++rounds > (1 << 12)) break;
        __builtin_amdgcn_s_sleep(1);
        #pragma unroll
        for (int j = 0; j < 8; ++j) if (inval & (1u << j)) GL16_SC1(ch1[j], hb1 + j * 32);
        asm volatile("s_waitcnt vmcnt(0)" ::: "memory");
        __builtin_amdgcn_sched_barrier(0);
      }
    }
    f16x8 B1[8];
    #pragma unroll
    for (int j = 0; j < 8; ++j) B1[j] = __builtin_bit_cast(f16x8, ch1[j]);

    if (rot) {  // prefetch next step's A-half (buffer t+1; A published mid-step)
      const _Float16* hb0n = hT + (size_t)(t + 1) * HB
                           + (size_t)(c0 + rlo) * H_ + kg * 256 + q * 8;
      #pragma unroll
      for (int j = 0; j < 8; ++j) GL16_SC1(ch0[j], hb0n + j * 32);
    }

    f32x4 accB[4];
    #pragma unroll
    for (int mt = 0; mt < 4; ++mt) accB[mt] = (f32x4){0.f,0.f,0.f,0.f};
    #pragma unroll
    for (int kkl = 0; kkl < 8; ++kkl)
      #pragma unroll
      for (int mt = 0; mt < 4; ++mt)
        accB[mt] = __builtin_amdgcn_mfma_f32_16x16x32_f16(A[mt*8+kkl], B1[kkl], accB[mt], 0,0,0);

    #pragma unroll
    for (int mt = 0; mt < 4; ++mt) {
      const int m = mg * 64 + mt * 16 + 4 * q;
      unsigned addr = (unsigned)(rlo * 2048 + kg * 512 + m * 4);
      addr ^= (unsigned)((rlo & 7) << 4);
      *reinterpret_cast<f32x4*>(reinterpret_cast<char*>(part) + addr) = accB[mt];
    }
    if (rot) { asm volatile("s_waitcnt lgkmcnt(0)" ::: "memory"); __builtin_amdgcn_s_barrier(); }
    else __syncthreads();

    {
      unsigned lin = (unsigned)(cA * 2048 + un * 16);
      f32x4 s = *reinterpret_cast<const f32x4*>(
          reinterpret_cast<const char*>(part) + (lin ^ ((unsigned)(cA & 7) << 4)));
      #pragma unroll
      for (int kgi = 1; kgi < 4; ++kgi) {
        unsigned l2 = lin + (unsigned)(kgi * 512);
        s += *reinterpret_cast<const f32x4*>(
            reinterpret_cast<const char*>(part) + (l2 ^ ((unsigned)(cA & 7) << 4)));
      }
      const float xv = xl[(16 + cA) * T_ + t];
      float pg = s[0] + wx[0]*xv + bb[0];
      float pi = s[1] + wx[1]*xv + bb[1];
      float pf = s[2] + wx[2]*xv + bb[2];
      float po = s[3] + wx[3]*xv + bb[3];
      float gg = tanh_f(pg), ii = sigm_f(pi), ff = sigm_f(pf), oo = sigm_f(po);
      csB = gg * ii + csB * ff;
      unsigned short hbits = __builtin_bit_cast(unsigned short, (_Float16)(tanh_f(csB) * oo));
      int nb = __shfl_down((int)hbits, 1);
      if (!(un & 1)) {
        unsigned v = (unsigned)hbits | ((unsigned)(unsigned short)nb << 16);
        __hip_atomic_store(reinterpret_cast<unsigned*>(
            hbw + (size_t)(c0 + 16 + cA) * H_ + r * 32 + un),
            v, __ATOMIC_RELAXED, __HIP_MEMORY_SCOPE_AGENT);
      }
      asm volatile("" ::: "memory");
    }
    if (!rot) {
      asm volatile("s_waitcnt vmcnt(0)" ::: "memory");
      __syncthreads();
      if (tid == 0) __hip_atomic_store(ownflag, 2u*(unsigned)t + 2u,
                                       __ATOMIC_RELAXED, __HIP_MEMORY_SCOPE_AGENT);
    } else {
      __builtin_amdgcn_s_barrier();
    }
  }

  asm volatile("s_waitcnt vmcnt(0)" ::: "memory");  // final h stores land
}

// out[b][cls] = sum_u W_ph[cls][u] * h_final[u][b] + b_p[cls]
__global__ void lstm_proj(const _Float16* __restrict__ hfin,
                          const float* __restrict__ Wph,
                          const float* __restrict__ bp,
                          float* __restrict__ out)
{
  const int b = blockIdx.x;
  const int l = threadIdx.x;
  const _Float16* hrow = hfin + (size_t)b * H_;
  float p[C_];
  #pragma unroll
  for (int cls = 0; cls < C_; ++cls) p[cls] = 0.f;
  for (int u = l; u < H_; u += 64) {
    float hv = (float)hrow[u];
    #pragma unroll
    for (int cls = 0; cls < C_; ++cls) p[cls] += hv * Wph[cls * H_ + u];
  }
  #pragma unroll
  for (int cls = 0; cls < C_; ++cls) {
    float v = p[cls];
    #pragma unroll
    for (int off = 32; off > 0; off >>= 1) v += __shfl_down(v, off);
    if (l == 0) out[b * C_ + cls] = v + bp[cls];
  }
}

extern "C" void kernel_launch(void* const* d_in, const int* in_sizes, int n_in,
                              void* d_out, int out_size, void* d_ws, size_t ws_size,
                              hipStream_t stream) {
  const float* x   = (const float*)d_in[0];
  const float* Wgx = (const float*)d_in[1];
  const float* Wgh = (const float*)d_in[2];
  const float* Wix = (const float*)d_in[3];
  const float* Wih = (const float*)d_in[4];
  const float* Wfx = (const float*)d_in[5];
  const float* Wfh = (const float*)d_in[6];
  const float* Wox = (const float*)d_in[7];
  const float* Woh = (const float*)d_in[8];
  const float* Wph = (const float*)d_in[9];
  const float* bg  = (const float*)d_in[10];
  const float* bi  = (const float*)d_in[11];
  const float* bf  = (const float*)d_in[12];
  const float* bo  = (const float*)d_in[13];
  const float* bp  = (const float*)d_in[14];
  float* out = (float*)d_out;

  const size_t HB  = (size_t)B_ * H_;
  const size_t HBb = HB * sizeof(_Float16);        // 512 KiB per h buffer
  // ws: [0,16KB) flags (fallback only); [1MB, 1MB+257*512KB) h rotation
  const size_t need = (1u << 20) + 257 * HBb;      // ~129.5 MB
  const int rot = (ws_size >= need) ? 1 : 0;

  unsigned* flags = (unsigned*)d_ws;
  _Float16* hT    = (_Float16*)((char*)d_ws + (1u << 20));

  hipMemsetAsync(flags, 0, 16384, stream);         // fallback flags
  hipMemsetAsync(hT, 0, HBb, stream);              // buffer 0 = h(0) = 0
  if (rot)
    hipMemsetAsync((char*)hT + HBb, 0x7F, 256 * HBb, stream);  // sentinel fill
  else
    hipMemsetAsync((char*)hT + HBb, 0, HBb, stream);           // parity buf 1

  lstm_main<<<256, 512, 0, stream>>>(x, Wgh, Wih, Wfh, Woh,
                                     Wgx, Wix, Wfx, Wox,
                                     bg, bi, bf, bo, hT, flags, rot);
  lstm_proj<<<256, 64, 0, stream>>>(hT + (size_t)(rot ? T_ : 0) * HB,
                                    Wph, bp, out);
}